// Round 1
// 378.129 us; speedup vs baseline: 1.0798x; 1.0798x over previous
//
#include <hip/hip_runtime.h>
#include <math.h>

// FFT convolution: y[b,d,:] = (h[d] (*) x[b,d])[0:L] + x[b,d,:]*B[d]
// N=8192 packed-complex FFT per row in 64KB LDS. Register-blocked
// 4-stage passes, twiddles via one sincos + squaring chain, XOR bank
// swizzle (closed-form per pass), two-kernel split (H spectra in d_ws).
// R(this): fused ends — pass 1 loads straight from global (zero half
// folded in regs, no staging round-trip/barrier), last inverse pass
// writes y straight from registers (x kept in 8 float2 regs, no HBM
// re-read). Trivial twiddles (1, ∓i) specialized; swizzle arithmetic
// reduced to per-thread constants. LDS ops/thread 248->192, barriers 9->6.

#define FFT_N  8192
#define SEQ_L  8192
#define DIM_D  1024
#define NTHR   512

__device__ __forceinline__ float2 cadd(float2 a, float2 b){ return make_float2(a.x+b.x, a.y+b.y); }
__device__ __forceinline__ float2 csub(float2 a, float2 b){ return make_float2(a.x-b.x, a.y-b.y); }
__device__ __forceinline__ float2 cmul(float2 a, float2 b){ return make_float2(a.x*b.x - a.y*b.y, a.x*b.y + a.y*b.x); }
__device__ __forceinline__ int rev13(int k){ return (int)(__brev((unsigned)k) >> 19); }
// bank-conflict swizzle: spread bank-pair (i&15) with higher bits. bijective.
__device__ __forceinline__ int SW(int i){ return i ^ ((i >> 5) & 15) ^ ((i >> 9) & 15); }

// tw = exp(-i*m*pi/8) * w (DIF), trivial m folded (compiler can't fold *1/*0 w/o fast-math)
__device__ __forceinline__ float2 tw8_dif(int m, float2 w){
    constexpr float c[8] = {1.f, 0.92387953251f, 0.70710678119f, 0.38268343236f, 0.f, -0.38268343236f, -0.70710678119f, -0.92387953251f};
    constexpr float s[8] = {0.f, -0.38268343236f, -0.70710678119f, -0.92387953251f, -1.f, -0.92387953251f, -0.70710678119f, -0.38268343236f};
    if (m == 0) return w;
    if (m == 4) return make_float2(w.y, -w.x);            // (-i)*w
    return cmul(make_float2(c[m], s[m]), w);
}
// tw = exp(+i*m*pi/8) * w (DIT)
__device__ __forceinline__ float2 tw8_dit(int m, float2 w){
    constexpr float c[8] = {1.f, 0.92387953251f, 0.70710678119f, 0.38268343236f, 0.f, -0.38268343236f, -0.70710678119f, -0.92387953251f};
    constexpr float s[8] = {0.f, 0.38268343236f, 0.70710678119f, 0.92387953251f, 1.f, 0.92387953251f, 0.70710678119f, 0.38268343236f};
    if (m == 0) return w;
    if (m == 4) return make_float2(-w.y, w.x);            // (+i)*w
    return cmul(make_float2(c[m], s[m]), w);
}

// ---- DIF stage over bit3 of the owned 4 bits (8 butterflies)
__device__ __forceinline__ void dif_stage8(float2 v[16], float2 w){
    #pragma unroll
    for (int m = 0; m < 8; ++m){
        float2 tw = tw8_dif(m, w);
        float2 u = v[m], t = v[m+8];
        v[m] = cadd(u,t);
        v[m+8] = cmul(csub(u,t), tw);
    }
}

// ---- remaining 3 DIF stages; w here is base^2
__device__ __forceinline__ void dif_tail3(float2 v[16], float2 w){
    {   // stage over bit2: c4 twiddles * w, m=0/m=2 specialized, hoisted out of h-loop
        float2 t0 = w;
        float2 t1 = cmul(make_float2(0.70710678119f, -0.70710678119f), w);
        float2 t2 = make_float2(w.y, -w.x);
        float2 t3 = cmul(make_float2(-0.70710678119f, -0.70710678119f), w);
        #pragma unroll
        for (int h = 0; h < 16; h += 8){
            { float2 u=v[h+0], t=v[h+4]; v[h+0]=cadd(u,t); v[h+4]=cmul(csub(u,t), t0); }
            { float2 u=v[h+1], t=v[h+5]; v[h+1]=cadd(u,t); v[h+5]=cmul(csub(u,t), t1); }
            { float2 u=v[h+2], t=v[h+6]; v[h+2]=cadd(u,t); v[h+6]=cmul(csub(u,t), t2); }
            { float2 u=v[h+3], t=v[h+7]; v[h+3]=cadd(u,t); v[h+7]=cmul(csub(u,t), t3); }
        }
    }
    w = cmul(w,w);
    #pragma unroll
    for (int q = 0; q < 16; q += 4){
        { float2 u=v[q+0], t=v[q+2]; v[q+0]=cadd(u,t); v[q+2]=cmul(csub(u,t), w); }
        { float2 u=v[q+1], t=v[q+3]; float2 tw=make_float2(w.y,-w.x);
          v[q+1]=cadd(u,t); v[q+3]=cmul(csub(u,t), tw); }
    }
    w = cmul(w,w);
    #pragma unroll
    for (int e = 0; e < 16; e += 2){
        float2 u=v[e], t=v[e+1];
        v[e]=cadd(u,t); v[e+1]=cmul(csub(u,t), w);
    }
}

__device__ __forceinline__ void dif_pass4(float2 v[16], float2 w){
    dif_stage8(v, w);
    dif_tail3(v, cmul(w,w));
}

// ---- 4 radix-2 DIT (inverse, +i) stages in registers.
__device__ __forceinline__ void dit_pass4(float2 v[16], float2 w3){
    float2 w2 = cmul(w3,w3), w1 = cmul(w2,w2), w0 = cmul(w1,w1);
    #pragma unroll
    for (int e = 0; e < 16; e += 2){
        float2 t = cmul(v[e+1], w0);
        float2 u = v[e];
        v[e] = cadd(u,t); v[e+1] = csub(u,t);
    }
    #pragma unroll
    for (int q = 0; q < 16; q += 4){
        { float2 t = cmul(v[q+2], w1); float2 u=v[q+0]; v[q+0]=cadd(u,t); v[q+2]=csub(u,t); }
        { float2 tw = make_float2(-w1.y, w1.x);          // (+i)*w1
          float2 t = cmul(v[q+3], tw); float2 u=v[q+1]; v[q+1]=cadd(u,t); v[q+3]=csub(u,t); }
    }
    {   float2 t0 = w2;
        float2 t1 = cmul(make_float2(0.70710678119f, 0.70710678119f), w2);
        float2 t2 = make_float2(-w2.y, w2.x);
        float2 t3 = cmul(make_float2(-0.70710678119f, 0.70710678119f), w2);
        #pragma unroll
        for (int h = 0; h < 16; h += 8){
            { float2 t=cmul(v[h+4], t0); float2 u=v[h+0]; v[h+0]=cadd(u,t); v[h+4]=csub(u,t); }
            { float2 t=cmul(v[h+5], t1); float2 u=v[h+1]; v[h+1]=cadd(u,t); v[h+5]=csub(u,t); }
            { float2 t=cmul(v[h+6], t2); float2 u=v[h+2]; v[h+2]=cadd(u,t); v[h+6]=csub(u,t); }
            { float2 t=cmul(v[h+7], t3); float2 u=v[h+3]; v[h+3]=cadd(u,t); v[h+7]=csub(u,t); }
        }
    }
    #pragma unroll
    for (int m = 0; m < 8; ++m){
        float2 tw = tw8_dit(m, w3);
        float2 t = cmul(v[m+8], tw);
        float2 u = v[m];
        v[m] = cadd(u,t); v[m+8] = csub(u,t);
    }
}

// forward stages 0..11, pass 1 fused with the global load (top half is the
// zero pad -> stage 1 is just v[m+8]=v[m]*tw, no staging round trip).
// SAVEX: keep the 8 loaded x values in registers for the caller's epilogue.
// Swizzle closed forms (verified == SW(physical) for each pass):
//   pass A (stride 512): SW((k<<9)|tid)        = (k<<9) | (T1 ^ k),  T1 = tid ^ ((tid>>5)&15)
//   pass B (stride 32):  SW((hi<<9)|(k<<5)|lo) = (hi<<9)|(k<<5)|(TB ^ k), TB = lo ^ hi
//   pass C (stride 2):   SW((h2<<5)|(k<<1)|b0) = (h2<<5) | (((k<<1)|b0) ^ M3), M3 = (h2 ^ (h2>>4)) & 15
template<bool SAVEX>
__device__ __forceinline__ void fwd_fft12_fused(float2* z, const float2* __restrict__ row,
                                                int tid, float2* xs){
    float2 v[16];
    float sn, cs;
    __sincosf(-(float)M_PI * (float)tid * (1.0f/4096.0f), &sn, &cs);
    float2 w = make_float2(cs, sn);
    const int T1 = tid ^ ((tid >> 5) & 15);
    #pragma unroll
    for (int k = 0; k < 8; ++k){
        v[k] = row[(k<<9) | tid];
        if (SAVEX) xs[k] = v[k];
    }
    // stage 1 with zero top half: upper arm = v[m]*tw, lower arm unchanged
    #pragma unroll
    for (int m = 0; m < 8; ++m) v[m+8] = cmul(v[m], tw8_dif(m, w));
    dif_tail3(v, cmul(w,w));
    #pragma unroll
    for (int k = 0; k < 16; ++k) z[(k<<9) | (T1 ^ k)] = v[k];
    __syncthreads();

    const int hi = tid >> 5, lo = tid & 31;
    const int baseB = hi << 9, TB = lo ^ hi;
    __sincosf(-(float)M_PI * (float)lo * (1.0f/256.0f), &sn, &cs);
    w = make_float2(cs, sn);
    #pragma unroll
    for (int k = 0; k < 16; ++k) v[k] = z[baseB | (k<<5) | (TB ^ k)];
    dif_pass4(v, w);
    #pragma unroll
    for (int k = 0; k < 16; ++k) z[baseB | (k<<5) | (TB ^ k)] = v[k];
    __syncthreads();

    const int h2 = tid >> 1, b0 = tid & 1;
    const int baseC = h2 << 5, M3 = (h2 ^ (h2 >> 4)) & 15;
    w = b0 ? make_float2(0.98078528040f, -0.19509032202f)   // exp(-i pi/16)
           : make_float2(1.f, 0.f);
    #pragma unroll
    for (int k = 0; k < 16; ++k) v[k] = z[baseC | (((k<<1)|b0) ^ M3)];
    dif_pass4(v, w);
    #pragma unroll
    for (int k = 0; k < 16; ++k) z[baseC | (((k<<1)|b0) ^ M3)] = v[k];
    __syncthreads();
}

// real-FFT untangle: from Z[rev(p)], Z[rev(N-p)] produce A=E+tO, G=E-tO
__device__ __forceinline__ void untangle(float2 zk, float2 znk, float2 t, float2& A, float2& G){
    float2 E  = make_float2(0.5f*(zk.x+znk.x), 0.5f*(zk.y-znk.y));
    float2 O  = make_float2(0.5f*(zk.y+znk.y), -0.5f*(zk.x-znk.x));
    float2 tO = cmul(t, O);
    A = cadd(E, tO); G = csub(E, tO);
}

// untangle x, multiply with H (Ah,Gh), repack packed-inverse spectrum pair
__device__ __forceinline__ void pointmul(float2 zk, float2 znk, float2 t,
                                         float2 Ah, float2 Gh, float invN,
                                         float2& Wp, float2& Wm){
    float2 Xp, Xm; untangle(zk, znk, t, Xp, Xm);
    float2 Cp = cmul(Ah, Xp), Cm = cmul(Gh, Xm);
    float2 S  = make_float2(0.5f*(Cp.x+Cm.x), 0.5f*(Cp.y+Cm.y));
    float2 Dd = make_float2(0.5f*(Cp.x-Cm.x), 0.5f*(Cp.y-Cm.y));
    float2 u  = make_float2(t.y*Dd.x - t.x*Dd.y, t.y*Dd.y + t.x*Dd.x); // i*conj(t)*Dd
    Wp = make_float2((S.x+u.x)*invN, (S.y+u.y)*invN);
    Wm = make_float2((S.x-u.x)*invN, -((S.y-u.y)*invN));
}

// ===================== kernel A: H spectra, once per d =====================
__global__ __launch_bounds__(NTHR)
void h_spec_kernel(const float* __restrict__ h,
                   float4* __restrict__ p0, float4* __restrict__ p1,
                   float2* __restrict__ hs2)
{
    __shared__ float2 z[FFT_N];
    const int tid = (int)threadIdx.x;
    const int d   = (int)blockIdx.x;
    const float2* hrow = (const float2*)(h + (size_t)d * SEQ_L);

    float2 dummy[8];
    fwd_fft12_fused<false>(z, hrow, tid, dummy);

    const size_t base = (size_t)d * 2048;
    #pragma unroll
    for (int q = 0; q < 4; ++q){
        int g = tid + NTHR * q;
        float2 A1, G1, A2, G2;
        if (g == 0){
            float2 z0 = z[SW(0)], z1 = z[SW(1)], z2 = z[SW(2)], z3 = z[SW(3)];
            float2 Z0 = cadd(z0,z1), Z1 = csub(z0,z1), Z2 = cadd(z2,z3), Z3 = csub(z2,z3);
            float2 A3, G3;
            untangle(Z0, Z0, make_float2(1.f, 0.f), A1, G1);                        // p=0
            untangle(Z2, Z3, make_float2(0.70710678119f, -0.70710678119f), A2, G2); // p=2048
            untangle(Z1, Z1, make_float2(0.f, -1.f), A3, G3);                       // p=4096
            hs2[(size_t)d*2 + 0] = A3;
            hs2[(size_t)d*2 + 1] = G3;
        } else {
            int a = rev13(g), c = rev13(4096 - g);
            float2 za = z[SW(a)], zb = z[SW(a+1)], zc = z[SW(c)], zd = z[SW(c+1)];
            float2 Z12a = cadd(za,zb), Z12b = csub(za,zb);
            float2 Z12c = cadd(zc,zd), Z12d = csub(zc,zd);
            float sn, cs; __sincosf(-(float)M_PI * (float)g * (1.0f/8192.0f), &sn, &cs);
            float2 t1 = make_float2(cs, sn), t2 = make_float2(-sn, -cs);
            untangle(Z12a, Z12d, t1, A1, G1);   // pair (g, 8192-g)
            untangle(Z12c, Z12b, t2, A2, G2);   // pair (4096-g, 4096+g)
        }
        p0[base + q*NTHR + tid] = make_float4(A1.x, A1.y, G1.x, G1.y);
        p1[base + q*NTHR + tid] = make_float4(A2.x, A2.y, G2.x, G2.y);
    }
}

// ===================== kernel B: x FFT + pointwise + inverse =====================
__global__ __launch_bounds__(NTHR)
void fftconv_x_kernel(const float* __restrict__ x,
                      const float* __restrict__ Bv,
                      float* __restrict__ y,
                      const float4* __restrict__ p0, const float4* __restrict__ p1,
                      const float2* __restrict__ hs2)
{
    __shared__ float2 z[FFT_N];
    const int tid = (int)threadIdx.x;
    const int d   = (int)blockIdx.x;
    const int b   = (int)blockIdx.y;

    const float Bd = Bv[d];
    const float2* xrow = (const float2*)(x + ((size_t)b * DIM_D + (size_t)d) * SEQ_L);
    float2*       yrow = (float2*)(y + ((size_t)b * DIM_D + (size_t)d) * SEQ_L);
    const float invN = 1.0f / (float)FFT_N;

    float2 xs[8];                       // x kept in regs for the epilogue (no HBM re-read)
    fwd_fft12_fused<true>(z, xrow, tid, xs);

    // fused middle: fwd stage12 + untangle + multiply + repack + inv stage0.
    const size_t base = (size_t)d * 2048;
    #pragma unroll
    for (int q = 0; q < 4; ++q){
        int g = tid + NTHR * q;
        float4 f0 = p0[base + q*NTHR + tid];
        float4 f1 = p1[base + q*NTHR + tid];
        float2 Ah1 = make_float2(f0.x, f0.y), Gh1 = make_float2(f0.z, f0.w);
        float2 Ah2 = make_float2(f1.x, f1.y), Gh2 = make_float2(f1.z, f1.w);
        if (g == 0){
            float2 A3 = hs2[(size_t)d*2 + 0], G3 = hs2[(size_t)d*2 + 1];
            float2 z0 = z[SW(0)], z1 = z[SW(1)], z2 = z[SW(2)], z3 = z[SW(3)];
            float2 Z0 = cadd(z0,z1), Z1 = csub(z0,z1), Z2 = cadd(z2,z3), Z3 = csub(z2,z3);
            float2 W0, W0b, W1, W1b, W2, W3;
            pointmul(Z0, Z0, make_float2(1.f, 0.f),  Ah1, Gh1, invN, W0, W0b);
            pointmul(Z1, Z1, make_float2(0.f, -1.f), A3,  G3,  invN, W1, W1b);
            pointmul(Z2, Z3, make_float2(0.70710678119f, -0.70710678119f), Ah2, Gh2, invN, W2, W3);
            z[SW(0)] = cadd(W0, W1);
            z[SW(1)] = csub(W0, W1);
            z[SW(2)] = cadd(W2, W3);
            z[SW(3)] = csub(W2, W3);
        } else {
            int a = rev13(g), c = rev13(4096 - g);
            float2 za = z[SW(a)], zb = z[SW(a+1)], zc = z[SW(c)], zd = z[SW(c+1)];
            float2 Z12a = cadd(za,zb), Z12b = csub(za,zb);
            float2 Z12c = cadd(zc,zd), Z12d = csub(zc,zd);
            float sn, cs; __sincosf(-(float)M_PI * (float)g * (1.0f/8192.0f), &sn, &cs);
            float2 t1 = make_float2(cs, sn), t2 = make_float2(-sn, -cs);
            float2 Wp1, Wm1, Wp2, Wm2;
            pointmul(Z12a, Z12d, t1, Ah1, Gh1, invN, Wp1, Wm1);
            pointmul(Z12c, Z12b, t2, Ah2, Gh2, invN, Wp2, Wm2);
            z[SW(a)]   = cadd(Wp1, Wm2);
            z[SW(a+1)] = csub(Wp1, Wm2);
            z[SW(c)]   = cadd(Wp2, Wm1);
            z[SW(c+1)] = csub(Wp2, Wm1);
        }
    }
    __syncthreads();

    // inverse stages 1..12; last pass fused with the y-store (v[8..15] arm DCE'd)
    {
        float2 v[16];
        float sn, cs;
        const int h2 = tid >> 1, b0 = tid & 1, hi = tid >> 5, lo = tid & 31;
        const int baseC = h2 << 5, M3 = (h2 ^ (h2 >> 4)) & 15;
        float2 w3 = b0 ? make_float2(0.98078528040f, 0.19509032202f)  // exp(+i pi/16)
                       : make_float2(1.f, 0.f);
        #pragma unroll
        for (int k = 0; k < 16; ++k) v[k] = z[baseC | (((k<<1)|b0) ^ M3)];
        dit_pass4(v, w3);
        #pragma unroll
        for (int k = 0; k < 16; ++k) z[baseC | (((k<<1)|b0) ^ M3)] = v[k];
        __syncthreads();
        const int baseB = hi << 9, TB = lo ^ hi;
        __sincosf((float)M_PI * (float)lo * (1.0f/256.0f), &sn, &cs);
        w3 = make_float2(cs, sn);
        #pragma unroll
        for (int k = 0; k < 16; ++k) v[k] = z[baseB | (k<<5) | (TB ^ k)];
        dit_pass4(v, w3);
        #pragma unroll
        for (int k = 0; k < 16; ++k) z[baseB | (k<<5) | (TB ^ k)] = v[k];
        __syncthreads();
        const int T1 = tid ^ ((tid >> 5) & 15);
        __sincosf((float)M_PI * (float)tid * (1.0f/4096.0f), &sn, &cs);
        w3 = make_float2(cs, sn);
        #pragma unroll
        for (int k = 0; k < 16; ++k) v[k] = z[(k<<9) | (T1 ^ k)];
        dit_pass4(v, w3);
        #pragma unroll
        for (int k = 0; k < 8; ++k){
            int n = (k<<9) | tid;
            yrow[n] = make_float2(v[k].x + xs[k].x * Bd, v[k].y + xs[k].y * Bd);
        }
    }
}

// ============== fallback: single fused kernel (if ws too small) ==============
__global__ __launch_bounds__(NTHR)
void fftconv_fused(const float* __restrict__ h,
                   const float* __restrict__ x,
                   const float* __restrict__ Bv,
                   float* __restrict__ y)
{
    __shared__ float2 z[FFT_N];
    const int tid = (int)threadIdx.x;
    const int d   = (int)blockIdx.x;
    const int b   = (int)blockIdx.y;

    const float Bd = Bv[d];
    const float2* hrow = (const float2*)(h + (size_t)d * SEQ_L);
    const float2* xrow = (const float2*)(x + ((size_t)b * DIM_D + (size_t)d) * SEQ_L);
    float2*       yrow = (float2*)(y + ((size_t)b * DIM_D + (size_t)d) * SEQ_L);
    const float invN = 1.0f / (float)FFT_N;

    float2 dummy[8];
    fwd_fft12_fused<false>(z, hrow, tid, dummy);

    float2 Ah1[4], Gh1[4], Ah2[4], Gh2[4], Ah3, Gh3;
    #pragma unroll
    for (int q = 0; q < 4; ++q){
        int g = tid + NTHR * q;
        if (g == 0){
            float2 z0 = z[SW(0)], z1 = z[SW(1)], z2 = z[SW(2)], z3 = z[SW(3)];
            float2 Z0 = cadd(z0,z1), Z1 = csub(z0,z1), Z2 = cadd(z2,z3), Z3 = csub(z2,z3);
            untangle(Z0, Z0, make_float2(1.f, 0.f), Ah1[0], Gh1[0]);
            untangle(Z2, Z3, make_float2(0.70710678119f, -0.70710678119f), Ah2[0], Gh2[0]);
            untangle(Z1, Z1, make_float2(0.f, -1.f), Ah3, Gh3);
        } else {
            int a = rev13(g), c = rev13(4096 - g);
            float2 za = z[SW(a)], zb = z[SW(a+1)], zc = z[SW(c)], zd = z[SW(c+1)];
            float2 Z12a = cadd(za,zb), Z12b = csub(za,zb);
            float2 Z12c = cadd(zc,zd), Z12d = csub(zc,zd);
            float sn, cs; __sincosf(-(float)M_PI * (float)g * (1.0f/8192.0f), &sn, &cs);
            float2 t1 = make_float2(cs, sn), t2 = make_float2(-sn, -cs);
            untangle(Z12a, Z12d, t1, Ah1[q], Gh1[q]);
            untangle(Z12c, Z12b, t2, Ah2[q], Gh2[q]);
        }
    }
    __syncthreads();

    fwd_fft12_fused<false>(z, xrow, tid, dummy);

    #pragma unroll
    for (int q = 0; q < 4; ++q){
        int g = tid + NTHR * q;
        if (g == 0){
            float2 z0 = z[SW(0)], z1 = z[SW(1)], z2 = z[SW(2)], z3 = z[SW(3)];
            float2 Z0 = cadd(z0,z1), Z1 = csub(z0,z1), Z2 = cadd(z2,z3), Z3 = csub(z2,z3);
            float2 W0, W0b, W1, W1b, W2, W3;
            pointmul(Z0, Z0, make_float2(1.f, 0.f),  Ah1[0], Gh1[0], invN, W0, W0b);
            pointmul(Z1, Z1, make_float2(0.f, -1.f), Ah3,    Gh3,    invN, W1, W1b);
            pointmul(Z2, Z3, make_float2(0.70710678119f, -0.70710678119f), Ah2[0], Gh2[0], invN, W2, W3);
            z[SW(0)] = cadd(W0, W1);
            z[SW(1)] = csub(W0, W1);
            z[SW(2)] = cadd(W2, W3);
            z[SW(3)] = csub(W2, W3);
        } else {
            int a = rev13(g), c = rev13(4096 - g);
            float2 za = z[SW(a)], zb = z[SW(a+1)], zc = z[SW(c)], zd = z[SW(c+1)];
            float2 Z12a = cadd(za,zb), Z12b = csub(za,zb);
            float2 Z12c = cadd(zc,zd), Z12d = csub(zc,zd);
            float sn, cs; __sincosf(-(float)M_PI * (float)g * (1.0f/8192.0f), &sn, &cs);
            float2 t1 = make_float2(cs, sn), t2 = make_float2(-sn, -cs);
            float2 Wp1, Wm1, Wp2, Wm2;
            pointmul(Z12a, Z12d, t1, Ah1[q], Gh1[q], invN, Wp1, Wm1);
            pointmul(Z12c, Z12b, t2, Ah2[q], Gh2[q], invN, Wp2, Wm2);
            z[SW(a)]   = cadd(Wp1, Wm2);
            z[SW(a+1)] = csub(Wp1, Wm2);
            z[SW(c)]   = cadd(Wp2, Wm1);
            z[SW(c+1)] = csub(Wp2, Wm1);
        }
    }
    __syncthreads();

    {
        float2 v[16];
        float sn, cs;
        const int h2 = tid >> 1, b0 = tid & 1, hi = tid >> 5, lo = tid & 31;
        const int baseC = h2 << 5, M3 = (h2 ^ (h2 >> 4)) & 15;
        float2 w3 = b0 ? make_float2(0.98078528040f, 0.19509032202f)
                       : make_float2(1.f, 0.f);
        #pragma unroll
        for (int k = 0; k < 16; ++k) v[k] = z[baseC | (((k<<1)|b0) ^ M3)];
        dit_pass4(v, w3);
        #pragma unroll
        for (int k = 0; k < 16; ++k) z[baseC | (((k<<1)|b0) ^ M3)] = v[k];
        __syncthreads();
        const int baseB = hi << 9, TB = lo ^ hi;
        __sincosf((float)M_PI * (float)lo * (1.0f/256.0f), &sn, &cs);
        w3 = make_float2(cs, sn);
        #pragma unroll
        for (int k = 0; k < 16; ++k) v[k] = z[baseB | (k<<5) | (TB ^ k)];
        dit_pass4(v, w3);
        #pragma unroll
        for (int k = 0; k < 16; ++k) z[baseB | (k<<5) | (TB ^ k)] = v[k];
        __syncthreads();
        const int T1 = tid ^ ((tid >> 5) & 15);
        __sincosf((float)M_PI * (float)tid * (1.0f/4096.0f), &sn, &cs);
        w3 = make_float2(cs, sn);
        #pragma unroll
        for (int k = 0; k < 16; ++k) v[k] = z[(k<<9) | (T1 ^ k)];
        dit_pass4(v, w3);
        #pragma unroll
        for (int k = 0; k < 8; ++k){
            int n = (k<<9) | tid;
            float2 xv = xrow[n];
            yrow[n] = make_float2(v[k].x + xv.x * Bd, v[k].y + xv.y * Bd);
        }
    }
}

extern "C" void kernel_launch(void* const* d_in, const int* in_sizes, int n_in,
                              void* d_out, int out_size, void* d_ws, size_t ws_size,
                              hipStream_t stream) {
    const float* h  = (const float*)d_in[0];
    const float* x  = (const float*)d_in[1];
    const float* Bv = (const float*)d_in[2];
    float* y = (float*)d_out;

    const int bsz = out_size / (DIM_D * SEQ_L);   // = 4
    const size_t plane = (size_t)DIM_D * 2048;    // float4 elements per plane
    const size_t need  = plane * 2 * sizeof(float4) + (size_t)DIM_D * 2 * sizeof(float2);

    if (ws_size >= need) {
        float4* p0  = (float4*)d_ws;
        float4* p1  = p0 + plane;
        float2* hs2 = (float2*)(p1 + plane);
        hipLaunchKernelGGL(h_spec_kernel, dim3(DIM_D), dim3(NTHR), 0, stream, h, p0, p1, hs2);
        hipLaunchKernelGGL(fftconv_x_kernel, dim3(DIM_D, bsz), dim3(NTHR), 0, stream,
                           x, Bv, y, p0, p1, hs2);
    } else {
        hipLaunchKernelGGL(fftconv_fused, dim3(DIM_D, bsz), dim3(NTHR), 0, stream, h, x, Bv, y);
    }
}